// Round 7
// baseline (333.688 us; speedup 1.0000x reference)
//
#include <hip/hip_runtime.h>
#include <stdint.h>

// RWKV TimeMixing on gfx950. I/O dtype: float32 (per reference).
// Internal: bf16 for MFMA GEMMs + k/v/rsig storage, f32 for WKV scan state.
// R11: GEMM K-tile restructured 8 barriers -> 3 (windows 16/32/16 MFMA).
// Model: R10's 5550 cyc/tile = LDS(2300) + MFMA(2480) fully serialized by the
// [flood][bar][drain][MFMA][bar] phase shape (s_barrier = sched boundary).
// Fewer boundaries let wave-stagger overlap LDS and matrix pipes.
// Invariants preserved from proven R8/R10 (R9 lesson):
//  - every stage >=2 barriers after last read of its target buffer
//    (A-stage W2: SBAR3(t-1)+SBAR1(t); B-stage W3: SBAR1+SBAR2)
//  - counted VMW(4) (A issued before B -> leaves newest B(t+2) only),
//    clobbered, followed by SBAR3 = publish-before-read
// Scans/prep identical to R10.
// Launches: prep, gemmKV(z=2), gemmR, pass1, pass2, pass3, gemmO (7 total).
// Workspace layout (176 MiB):
//   [0,32M)     bufK bf16 (mix_k)
//   [32M,64M)   bufV bf16 (mix_v); rsig written here after gemmKV
//   [64M,96M)   bufR bf16 (mix_r); rwkv written here after gemmR
//   [96M,128M)  kb bf16
//   [128M,136M) wk/wv/wr/wo bf16 (2 MiB each)
//   [136M,142M) scan scratch: snum,sden,smx,inum,iden,imx (1 MiB each)
//   [142M,174M) vb bf16

using bf16x8 = __attribute__((ext_vector_type(8))) __bf16;
using f32x4  = __attribute__((ext_vector_type(4))) float;

union FU { float f; unsigned int u; };

__device__ __forceinline__ unsigned short f2b(float f) {
  FU v; v.f = f;
  unsigned int u = v.u;
  return (unsigned short)((u + 0x7fffu + ((u >> 16) & 1u)) >> 16);
}
__device__ __forceinline__ float b2f(unsigned short h) {
  FU v; v.u = ((unsigned int)h) << 16; return v.f;
}

__device__ __forceinline__ void gl_lds16(const unsigned short* g,
                                         const unsigned short* l) {
  __builtin_amdgcn_global_load_lds(
      (const __attribute__((address_space(1))) void*)g,
      (__attribute__((address_space(3))) void*)l, 16, 0, 0);
}

#define SBAR()  __builtin_amdgcn_s_barrier()
// Clobbered counted wait: pins reads below the drain point (R9 lesson) at
// measured-zero cost (R6 vs R8 A/B was neutral).
#define VMWC(n) asm volatile("s_waitcnt vmcnt(" #n ")" ::: "memory")

// ---------------- prep: wconv (blocks 0..4095) + mix3 (blocks 4096..12287) --
__global__ __launch_bounds__(256) void prep_kernel(
    const float* __restrict__ x,
    const float* __restrict__ w0, const float* __restrict__ w1,
    const float* __restrict__ w2, const float* __restrict__ w3,
    unsigned short* __restrict__ o0, unsigned short* __restrict__ o1,
    unsigned short* __restrict__ o2, unsigned short* __restrict__ o3,
    const float* __restrict__ mk, const float* __restrict__ mv,
    const float* __restrict__ mr,
    unsigned short* __restrict__ ok, unsigned short* __restrict__ ov,
    unsigned short* __restrict__ orr)
{
  int bid = blockIdx.x;
  if (bid < 4096) {
    int mat = bid >> 10, blk = bid & 1023;
    const float* src = (mat == 0) ? w0 : (mat == 1) ? w1 : (mat == 2) ? w2 : w3;
    unsigned short* dst = (mat == 0) ? o0 : (mat == 1) ? o1 : (mat == 2) ? o2 : o3;
    int i = blk * 1024 + threadIdx.x * 4;
    float4 v = *(const float4*)(src + i);
    union { int2 i2; unsigned short u[4]; } o;
    o.u[0] = f2b(v.x); o.u[1] = f2b(v.y); o.u[2] = f2b(v.z); o.u[3] = f2b(v.w);
    *(int2*)(dst + i) = o.i2;
    return;
  }
  int i = (bid - 4096) * 256 + threadIdx.x;
  int base = i * 8;             // C=1024, T=2048 compile-time facts
  int row = base >> 10;         // b*T + t
  int t = row & 2047;           // t within batch
  int c = base & 1023;
  float xv[8], pv[8];
  *(float4*)&xv[0] = *(const float4*)(x + base);
  *(float4*)&xv[4] = *(const float4*)(x + base + 4);
  if (t > 0) {
    *(float4*)&pv[0] = *(const float4*)(x + base - 1024);
    *(float4*)&pv[4] = *(const float4*)(x + base - 1024 + 4);
  } else {
#pragma unroll
    for (int e = 0; e < 8; ++e) pv[e] = 0.f;
  }
  float mkv[8], mvv[8], mrv[8];
  *(float4*)&mkv[0] = *(const float4*)(mk + c);
  *(float4*)&mkv[4] = *(const float4*)(mk + c + 4);
  *(float4*)&mvv[0] = *(const float4*)(mv + c);
  *(float4*)&mvv[4] = *(const float4*)(mv + c + 4);
  *(float4*)&mrv[0] = *(const float4*)(mr + c);
  *(float4*)&mrv[4] = *(const float4*)(mr + c + 4);
  union { int4 i4; unsigned short u[8]; } a, b2, d;
#pragma unroll
  for (int e = 0; e < 8; ++e) {
    float xe = xv[e], pe = pv[e];
    a.u[e]  = f2b(xe * mkv[e] + pe * (1.f - mkv[e]));
    b2.u[e] = f2b(xe * mvv[e] + pe * (1.f - mvv[e]));
    d.u[e]  = f2b(xe * mrv[e] + pe * (1.f - mrv[e]));
  }
  *(int4*)(ok + base)  = a.i4;
  *(int4*)(ov + base)  = b2.i4;
  *(int4*)(orr + base) = d.i4;
}

// ---------------- 256x256 BK=64 8-wave pipelined GEMM ----------------
// LDS layout per tile: [256 rows][64 bf16] row-major, 128 B/row, with XOR
// swizzle: physical 16B-slot = logical slot ^ (row & 7). Staged via
// global_load_lds (linear LDS dest) with the inverse permutation applied to
// the per-lane GLOBAL source address.

__device__ __forceinline__ void stageHalf(
    const unsigned short* __restrict__ g,  // matrix base + block-row base
    const unsigned short* l,               // LDS tile base (elements)
    int rh, int kt, int w, int rl, int koffel)
{
#pragma unroll
  for (int c = 0; c < 2; ++c) {
    int rows = rh * 128 + (2 * w + c) * 8;   // 8-row subtile base
    gl_lds16(g + (size_t)(rows + rl) * 1024 + kt * 64 + koffel,
             l + rows * 64);
  }
}

template<int Q>
__device__ __forceinline__ void quadMfma(f32x4 (&acc)[8][4],
    bf16x8 a00, bf16x8 a01, bf16x8 a10, bf16x8 a11, bf16x8 (&b)[4][2])
{
#pragma unroll
  for (int j = 0; j < 4; ++j) {
    acc[2*Q][j]   = __builtin_amdgcn_mfma_f32_16x16x32_bf16(a00, b[j][0], acc[2*Q][j],   0, 0, 0);
    acc[2*Q][j]   = __builtin_amdgcn_mfma_f32_16x16x32_bf16(a01, b[j][1], acc[2*Q][j],   0, 0, 0);
    acc[2*Q+1][j] = __builtin_amdgcn_mfma_f32_16x16x32_bf16(a10, b[j][0], acc[2*Q+1][j], 0, 0, 0);
    acc[2*Q+1][j] = __builtin_amdgcn_mfma_f32_16x16x32_bf16(a11, b[j][1], acc[2*Q+1][j], 0, 0, 0);
  }
}

// One K-tile = 3 windows / 3 barriers:
//  W1: reads b(8)+a0(4);            MFMA q0 (16); SBAR1
//  W2: reads a1,a2(8); stage A(t+1); MFMA q1,q2 (32); SBAR2
//  W3: reads a3(4);    stage B(t+2); MFMA q3 (16); VMWC; SBAR3
// Margins (>=2 barriers stage vs last-read of target, R9 lesson):
//  A(t+1)->aW: aW last read t-1 W3 -> SBAR3(t-1)+SBAR1(t) = 2.
//  B(t+2)->bW(==bR buffer): b-reads W1 -> SBAR1+SBAR2 = 2.
// vmcnt: per tile issues A(t+1)x4 (W2) then B(t+2)x4 (W3); VMWC(4) leaves
// exactly B(t+2) (newest), drains A(t+1)+B(t+1); SBAR3 publishes them.
template<bool ST_A, bool ST_B, int VMN, bool ENDBAR>
__device__ __forceinline__ void ktile3(
    const unsigned short* aR, const unsigned short* bR,
    const unsigned short* aW, const unsigned short* bW,
    const unsigned short* Am, const unsigned short* Wn,
    int ktA, int ktB, int w, int wm, int wn, int col, int quad,
    int swzel, int rl, int koffel, f32x4 (&acc)[8][4])
{
  const int ks0 = (quad * 8) ^ swzel;        // k-slice 0 slot (elements)
  const int ks1 = (32 + quad * 8) ^ swzel;   // k-slice 1 slot
  const unsigned short* ar = aR + (wm * 128 + col) * 64;

  // ---- Window 1: b + a0 reads; MFMA q0 ----
  bf16x8 b[4][2];
#pragma unroll
  for (int j = 0; j < 4; ++j) {
    const unsigned short* br = bR + (wn * 64 + j * 16 + col) * 64;
    b[j][0] = *(const bf16x8*)(br + ks0);
    b[j][1] = *(const bf16x8*)(br + ks1);
  }
  {
    bf16x8 a00 = *(const bf16x8*)(ar + 0 * 1024 + ks0);
    bf16x8 a01 = *(const bf16x8*)(ar + 0 * 1024 + ks1);
    bf16x8 a10 = *(const bf16x8*)(ar + 1 * 1024 + ks0);
    bf16x8 a11 = *(const bf16x8*)(ar + 1 * 1024 + ks1);
    __builtin_amdgcn_s_setprio(1);
    quadMfma<0>(acc, a00, a01, a10, a11, b);
    __builtin_amdgcn_s_setprio(0);
    SBAR();
  }
  // ---- Window 2: a1,a2 reads; stage A(t+1); MFMA q1,q2 ----
  {
    bf16x8 a10_ = *(const bf16x8*)(ar + 2 * 1024 + ks0);
    bf16x8 a11_ = *(const bf16x8*)(ar + 2 * 1024 + ks1);
    bf16x8 a12_ = *(const bf16x8*)(ar + 3 * 1024 + ks0);
    bf16x8 a13_ = *(const bf16x8*)(ar + 3 * 1024 + ks1);
    bf16x8 a20_ = *(const bf16x8*)(ar + 4 * 1024 + ks0);
    bf16x8 a21_ = *(const bf16x8*)(ar + 4 * 1024 + ks1);
    bf16x8 a22_ = *(const bf16x8*)(ar + 5 * 1024 + ks0);
    bf16x8 a23_ = *(const bf16x8*)(ar + 5 * 1024 + ks1);
    if (ST_A) {
      stageHalf(Am, aW, 0, ktA, w, rl, koffel);
      stageHalf(Am, aW, 1, ktA, w, rl, koffel);
    }
    __builtin_amdgcn_s_setprio(1);
    quadMfma<1>(acc, a10_, a11_, a12_, a13_, b);
    quadMfma<2>(acc, a20_, a21_, a22_, a23_, b);
    __builtin_amdgcn_s_setprio(0);
    SBAR();
  }
  // ---- Window 3: a3 reads; stage B(t+2); MFMA q3; VMW; SBAR ----
  {
    bf16x8 a30_ = *(const bf16x8*)(ar + 6 * 1024 + ks0);
    bf16x8 a31_ = *(const bf16x8*)(ar + 6 * 1024 + ks1);
    bf16x8 a32_ = *(const bf16x8*)(ar + 7 * 1024 + ks0);
    bf16x8 a33_ = *(const bf16x8*)(ar + 7 * 1024 + ks1);
    if (ST_B) {
      stageHalf(Wn, bW, 0, ktB, w, rl, koffel);
      stageHalf(Wn, bW, 1, ktB, w, rl, koffel);
    }
    __builtin_amdgcn_s_setprio(1);
    quadMfma<3>(acc, a30_, a31_, a32_, a33_, b);
    __builtin_amdgcn_s_setprio(0);
    if constexpr (VMN == 4) { VMWC(4); }
    else if constexpr (VMN == 0) { VMWC(0); }
    if constexpr (ENDBAR) { SBAR(); }
  }
}

template<typename EPI>
__device__ __forceinline__ void gemm256(
    const unsigned short* __restrict__ A,
    const unsigned short* __restrict__ W,
    EPI epi)
{
  __shared__ __align__(16) unsigned short As[2][256 * 64];
  __shared__ __align__(16) unsigned short Bs[2][256 * 64];
  const int tid  = threadIdx.x;
  const int lane = tid & 63;
  const int w    = tid >> 6;          // wave 0..7
  const int wm   = w >> 2, wn = w & 3;
  const int col  = lane & 15, quad = lane >> 4;
  const int swzel  = (lane & 7) << 3;            // read-side XOR (elements)
  const int rl     = lane >> 3;                  // staging row-in-subtile
  const int koffel = ((lane & 7) ^ rl) << 3;     // pre-swizzled global k-off
  const int mBase = blockIdx.x * 256;
  const int nBase = blockIdx.y * 256;
  const unsigned short* Am = A + (size_t)mBase * 1024;
  const unsigned short* Wn = W + (size_t)nBase * 1024;

  f32x4 acc[8][4];
  const f32x4 z = {0.f, 0.f, 0.f, 0.f};
#pragma unroll
  for (int i = 0; i < 8; ++i)
#pragma unroll
    for (int j = 0; j < 4; ++j) acc[i][j] = z;

  // Prologue: B(0), A(0), B(1) = 12 loads/thread; drain oldest 8 (B0,A0),
  // leave B(1) in flight; barrier publishes B0/A0 for tile 0.
  stageHalf(Wn, &Bs[0][0], 0, 0, w, rl, koffel);
  stageHalf(Wn, &Bs[0][0], 1, 0, w, rl, koffel);
  stageHalf(Am, &As[0][0], 0, 0, w, rl, koffel);
  stageHalf(Am, &As[0][0], 1, 0, w, rl, koffel);
  stageHalf(Wn, &Bs[1][0], 0, 1, w, rl, koffel);
  stageHalf(Wn, &Bs[1][0], 1, 1, w, rl, koffel);
  VMWC(4); SBAR();

#pragma unroll 1
  for (int t = 0; t < 14; t += 2) {
    ktile3<true, true, 4, true>(&As[0][0], &Bs[0][0], &As[1][0], &Bs[0][0],
                                Am, Wn, t + 1, t + 2,
                                w, wm, wn, col, quad, swzel, rl, koffel, acc);
    ktile3<true, true, 4, true>(&As[1][0], &Bs[1][0], &As[0][0], &Bs[1][0],
                                Am, Wn, t + 2, t + 3,
                                w, wm, wn, col, quad, swzel, rl, koffel, acc);
  }
  // t = 14: stage only A(15); drain everything at checkpoint.
  ktile3<true, false, 0, true>(&As[0][0], &Bs[0][0], &As[1][0], &Bs[0][0],
                               Am, Wn, 15, 0,
                               w, wm, wn, col, quad, swzel, rl, koffel, acc);
  // t = 15: pure compute; no trailing barrier (epilogue touches no LDS).
  ktile3<false, false, -1, false>(&As[1][0], &Bs[1][0], &As[0][0], &Bs[1][0],
                                  Am, Wn, 0, 0,
                                  w, wm, wn, col, quad, swzel, rl, koffel, acc);

  const int mB = mBase + wm * 128, nB = nBase + wn * 64;
#pragma unroll
  for (int i = 0; i < 8; ++i)
#pragma unroll
    for (int j = 0; j < 4; ++j)
#pragma unroll
      for (int r = 0; r < 4; ++r)
        epi(mB + i * 16 + quad * 4 + r, nB + j * 16 + col, acc[i][j][r]);
}

// fused K/V projection GEMM: z=0 -> kb, z=1 -> vb
__global__ __launch_bounds__(512, 2) void gemmKV2_kernel(
    const unsigned short* __restrict__ A0, const unsigned short* __restrict__ A1,
    const unsigned short* __restrict__ W0, const unsigned short* __restrict__ W1,
    unsigned short* __restrict__ out0, unsigned short* __restrict__ out1)
{
  const int z = blockIdx.z;
  const unsigned short* A = z ? A1 : A0;
  const unsigned short* W = z ? W1 : W0;
  unsigned short* out = z ? out1 : out0;
  gemm256(A, W, [&](int r, int c, float v) {
    out[(size_t)r * 1024 + c] = f2b(v);
  });
}

// R projection: sigmoid epilogue, bf16 out
__global__ __launch_bounds__(512, 2) void gemmR2_kernel(
    const unsigned short* __restrict__ A, const unsigned short* __restrict__ W,
    unsigned short* __restrict__ out)
{
  gemm256(A, W, [&](int r, int c, float v) {
    out[(size_t)r * 1024 + c] = f2b(1.0f / (1.0f + __expf(-v)));
  });
}

// final GEMM: f32 output
__global__ __launch_bounds__(512, 2) void gemmO2_kernel(
    const unsigned short* __restrict__ A, const unsigned short* __restrict__ W,
    float* __restrict__ out)
{
  gemm256(A, W, [&](int r, int c, float v) {
    out[(size_t)r * 1024 + c] = v;
  });
}

// ---------------- WKV chunked scan (NC=32 chunks of L=64) — R6 form ---------
__global__ __launch_bounds__(256) void wkv_pass1(
    const unsigned short* __restrict__ kb, const unsigned short* __restrict__ vb,
    const float* __restrict__ td,
    float* __restrict__ snum, float* __restrict__ sden, float* __restrict__ smx,
    int T, int C, int L)
{
  int g = blockIdx.x * 256 + threadIdx.x;
  int bc = g & 8191;
  int ch = g >> 13;
  int c = bc & 1023;
  float w = -__expf(td[c]);
  float num = 0.f, den = 0.f, mx = -1e38f;
  size_t base = ((size_t)(bc >> 10) * T + (size_t)ch * L) * C + c;
  for (int j0 = 0; j0 < L; j0 += 8) {
    float kq[8], vq[8];
#pragma unroll
    for (int j = 0; j < 8; ++j) {
      size_t a = base + (size_t)(j0 + j) * C;
      kq[j] = b2f(kb[a]);
      vq[j] = b2f(vb[a]);
    }
#pragma unroll
    for (int j = 0; j < 8; ++j) {
      float k = kq[j], v = vq[j];
      float mw = mx + w;
      float ms = fmaxf(mw, k);
      float s1 = __expf(mw - ms);
      float s2 = __expf(k - ms);
      num = s1 * num + s2 * v;
      den = s1 * den + s2;
      mx = ms;
    }
  }
  int idx = ch * 8192 + bc;
  snum[idx] = num; sden[idx] = den; smx[idx] = mx;
}

__global__ __launch_bounds__(64) void wkv_pass2(
    const float* __restrict__ snum, const float* __restrict__ sden,
    const float* __restrict__ smx, const float* __restrict__ td,
    float* __restrict__ inum, float* __restrict__ iden, float* __restrict__ imx,
    int L)
{
  int bc = blockIdx.x * 64 + threadIdx.x;
  int c = bc & 1023;
  float Wl = -__expf(td[c]) * (float)L;
  float num = 0.f, den = 0.f, mx = -1e38f;
#pragma unroll
  for (int ch = 0; ch < 32; ++ch) {
    int idx = ch * 8192 + bc;
    inum[idx] = num; iden[idx] = den; imx[idx] = mx;
    float sn = snum[idx], sd = sden[idx], sm = smx[idx];
    float mi = mx + Wl;
    float mo = fmaxf(mi, sm);
    float e1 = __expf(mi - mo);
    float e2 = __expf(sm - mo);
    num = e1 * num + e2 * sn;
    den = e1 * den + e2 * sd;
    mx = mo;
  }
}

__global__ __launch_bounds__(256) void wkv_pass3(
    const unsigned short* __restrict__ kb, const unsigned short* __restrict__ vb,
    const unsigned short* __restrict__ rsig,
    const float* __restrict__ td, const float* __restrict__ tf,
    const float* __restrict__ inum, const float* __restrict__ iden,
    const float* __restrict__ imx,
    unsigned short* __restrict__ rwkv, int T, int C, int L)
{
  int g = blockIdx.x * 256 + threadIdx.x;
  int bc = g & 8191;
  int ch = g >> 13;
  int c = bc & 1023;
  float w = -__expf(td[c]);
  float u = tf[c];
  int idx = ch * 8192 + bc;
  float num = inum[idx], den = iden[idx], mx = imx[idx];
  size_t base = ((size_t)(bc >> 10) * T + (size_t)ch * L) * C + c;
  for (int j0 = 0; j0 < L; j0 += 8) {
    float kq[8], vq[8], rq[8];
#pragma unroll
    for (int j = 0; j < 8; ++j) {
      size_t a = base + (size_t)(j0 + j) * C;
      kq[j] = b2f(kb[a]);
      vq[j] = b2f(vb[a]);
      rq[j] = b2f(rsig[a]);
    }
#pragma unroll
    for (int j = 0; j < 8; ++j) {
      float k = kq[j], v = vq[j];
      float ku = k + u;
      float mo = fmaxf(mx, ku);
      float e1 = __expf(mx - mo);
      float e2 = __expf(ku - mo);
      float o = (e1 * num + e2 * v) / (e1 * den + e2);
      rwkv[base + (size_t)(j0 + j) * C] = f2b(rq[j] * o);
      float mw = mx + w;
      float ms = fmaxf(mw, k);
      float s1 = __expf(mw - ms);
      float s2 = __expf(k - ms);
      num = s1 * num + s2 * v;
      den = s1 * den + s2;
      mx = ms;
    }
  }
}

extern "C" void kernel_launch(void* const* d_in, const int* in_sizes, int n_in,
                              void* d_out, int out_size, void* d_ws, size_t ws_size,
                              hipStream_t stream)
{
  const float* x  = (const float*)d_in[0];
  const float* wk = (const float*)d_in[1];
  const float* wv = (const float*)d_in[2];
  const float* wr = (const float*)d_in[3];
  const float* wo = (const float*)d_in[4];
  const float* td = (const float*)d_in[5];
  const float* tf = (const float*)d_in[6];
  const float* mk = (const float*)d_in[7];
  const float* mv = (const float*)d_in[8];
  const float* mr = (const float*)d_in[9];

  const int B = 8, T = 2048, C = 1024;
  const int M = B * T;      // 16384
  const int NC = 32, L = 64;
  const size_t MB = 1024 * 1024;

  char* ws = (char*)d_ws;
  unsigned short* bufK = (unsigned short*)(ws);              // 32 MiB
  unsigned short* bufV = (unsigned short*)(ws + 32 * MB);    // 32 MiB
  unsigned short* bufR = (unsigned short*)(ws + 64 * MB);    // 32 MiB
  unsigned short* kb   = (unsigned short*)(ws + 96 * MB);    // 32 MiB
  unsigned short* wkb  = (unsigned short*)(ws + 128 * MB);   // 2 MiB each
  unsigned short* wvb  = (unsigned short*)(ws + 130 * MB);
  unsigned short* wrb  = (unsigned short*)(ws + 132 * MB);
  unsigned short* wob  = (unsigned short*)(ws + 134 * MB);
  float* snum = (float*)(ws + 136 * MB);                     // 1 MiB each
  float* sden = (float*)(ws + 137 * MB);
  float* smx  = (float*)(ws + 138 * MB);
  float* inum = (float*)(ws + 139 * MB);
  float* iden = (float*)(ws + 140 * MB);
  float* imx  = (float*)(ws + 141 * MB);
  unsigned short* vb   = (unsigned short*)(ws + 142 * MB);   // 32 MiB
  // reuse (strictly after producer of the region is fully consumed):
  unsigned short* rsig = bufV;  // written by gemmR; bufV dead after gemmKV
  unsigned short* rwkv = bufR;  // written by pass3; bufR dead after gemmR

  dim3 gKV(M / 256, C / 256, 2);   // 64 x 4 x 2 = 512 blocks (2 clean rounds)
  dim3 gG(M / 256, C / 256);       // 64 x 4 = 256 blocks (1 round)
  int scanBlocks = (B * C * NC) / 256;  // 1024

  prep_kernel<<<12288, 256, 0, stream>>>(x, wk, wv, wr, wo, wkb, wvb, wrb, wob,
                                         mk, mv, mr, bufK, bufV, bufR);
  gemmKV2_kernel<<<gKV, 512, 0, stream>>>(bufK, bufV, wkb, wvb, kb, vb);
  gemmR2_kernel<<<gG, 512, 0, stream>>>(bufR, wrb, rsig);
  wkv_pass1<<<scanBlocks, 256, 0, stream>>>(kb, vb, td, snum, sden, smx, T, C, L);
  wkv_pass2<<<(B * C) / 64, 64, 0, stream>>>(snum, sden, smx, td, inum, iden, imx, L);
  wkv_pass3<<<scanBlocks, 256, 0, stream>>>(kb, vb, rsig, td, tf, inum, iden, imx,
                                            rwkv, T, C, L);
  gemmO2_kernel<<<gG, 512, 0, stream>>>(rwkv, wob, (float*)d_out);
}